// Round 5
// baseline (662.945 us; speedup 1.0000x reference)
//
#include <hip/hip_runtime.h>
#include <hip/hip_cooperative_groups.h>

#define HIDDEN 128
#define COOP_G 1024   // cooperative grid: 4 blocks/CU x 256 CUs
#define COOP_T 256

// ---------------------------------------------------------------------------
// One cooperative kernel: zero -> hist -> scan -> place  (5 grid syncs)
// Scan strategy: chunk = ceil(num_he/COOP_G) = 49 elements per block.
// Wave 0 of each block scans its chunk in-wave (registers persist across
// grid.sync), block 0 scans the 1024 block sums, then each block adds its
// base offset and writes offsets+cursor.
// ---------------------------------------------------------------------------
__global__ __launch_bounds__(COOP_T, 4) void build_csr(
    const int* __restrict__ he_index,   // [2, E] flat
    int* __restrict__ counts,           // [num_he]
    int* __restrict__ offsets,          // [num_he + 1]
    int* __restrict__ cursor,           // [num_he]
    int* __restrict__ block_sums,       // [COOP_G]
    int* __restrict__ sorted_node,      // [E]
    int E, int num_he) {
    cooperative_groups::grid_group grid = cooperative_groups::this_grid();
    const int tid  = blockIdx.x * COOP_T + threadIdx.x;
    const int nthr = COOP_G * COOP_T;

    // P0: zero the histogram (ws is poisoned 0xAA each call)
    for (int i = tid; i < num_he; i += nthr) counts[i] = 0;
    grid.sync();

    // P1: histogram of hyperedge degrees
    for (int e = tid; e < E; e += nthr) atomicAdd(&counts[he_index[E + e]], 1);
    grid.sync();

    // P2a: wave 0 of each block scans its chunk (<= 64 elements) in-wave
    const int chunk = (num_he + COOP_G - 1) / COOP_G;   // 49 for 50000/1024
    const int base  = blockIdx.x * chunk;
    int cnt = num_he - base;
    if (cnt > chunk) cnt = chunk;
    if (cnt < 0) cnt = 0;

    const int lane = threadIdx.x & 63;
    int v = 0, incl = 0;
    if (threadIdx.x < 64) {
        v = (lane < cnt) ? counts[base + lane] : 0;
        incl = v;
        #pragma unroll
        for (int off = 1; off < 64; off <<= 1) {
            int t = __shfl_up(incl, off, 64);
            if (lane >= off) incl += t;
        }
        int tot = __shfl(incl, 63, 64);   // lanes >= cnt contributed 0
        if (lane == 0) block_sums[blockIdx.x] = tot;
    }
    grid.sync();

    // P2b: block 0 exclusive-scans the COOP_G block sums (4 per thread)
    __shared__ int lds[COOP_T];
    if (blockIdx.x == 0) {
        const int t = threadIdx.x;
        int s0 = block_sums[4 * t + 0];
        int s1 = block_sums[4 * t + 1];
        int s2 = block_sums[4 * t + 2];
        int s3 = block_sums[4 * t + 3];
        int local = s0 + s1 + s2 + s3;
        lds[t] = local;
        __syncthreads();
        for (int off = 1; off < COOP_T; off <<= 1) {
            int tv = (t >= off) ? lds[t - off] : 0;
            __syncthreads();
            lds[t] += tv;
            __syncthreads();
        }
        int ex = lds[t] - local;
        block_sums[4 * t + 0] = ex;
        block_sums[4 * t + 1] = ex + s0;
        block_sums[4 * t + 2] = ex + s0 + s1;
        block_sums[4 * t + 3] = ex + s0 + s1 + s2;
    }
    grid.sync();

    // P2c: add block base, write offsets + cursor (v, incl live in registers)
    if (threadIdx.x < 64 && lane < cnt) {
        int o = block_sums[blockIdx.x] + incl - v;   // exclusive prefix
        offsets[base + lane] = o;
        cursor[base + lane]  = o;
    }
    if (tid == 0) offsets[num_he] = E;
    grid.sync();

    // P3: place node indices into CSR slots
    for (int e = tid; e < E; e += nthr) {
        int node = he_index[e];
        int he   = he_index[E + e];
        int pos  = atomicAdd(&cursor[he], 1);
        sorted_node[pos] = node;
    }
}

// ---------------------------------------------------------------------------
// Aggregate: one wave per hyperedge. Half-wave split: lanes 0-31 take even
// member slots, lanes 32-63 odd slots; each lane gathers float4 (16B).
// 2-deep unroll -> up to 4 independent 16B gathers in flight per lane.
// Combine halves with shfl, divide by clamped count, one float4 store.
// ---------------------------------------------------------------------------
__global__ __launch_bounds__(256) void aggregate_kernel(
    const float* __restrict__ node_feats,
    const int* __restrict__ offsets,
    const int* __restrict__ sorted_node,
    float* __restrict__ out,
    int num_he) {
    int wave = (blockIdx.x * blockDim.x + threadIdx.x) >> 6;
    int lane = threadIdx.x & 63;
    if (wave >= num_he) return;

    int start = offsets[wave];
    int end   = offsets[wave + 1];
    int half  = lane >> 5;
    int sub   = lane & 31;

    float4 a0 = make_float4(0.f, 0.f, 0.f, 0.f);
    float4 a1 = make_float4(0.f, 0.f, 0.f, 0.f);

    int j = start + half;              // this half's first slot
    for (; j + 2 < end; j += 4) {      // two stride-2 slots per iteration
        int n0 = sorted_node[j];
        int n1 = sorted_node[j + 2];
        float4 v0 = reinterpret_cast<const float4*>(
                        node_feats + (size_t)n0 * HIDDEN)[sub];
        float4 v1 = reinterpret_cast<const float4*>(
                        node_feats + (size_t)n1 * HIDDEN)[sub];
        a0.x += v0.x; a0.y += v0.y; a0.z += v0.z; a0.w += v0.w;
        a1.x += v1.x; a1.y += v1.y; a1.z += v1.z; a1.w += v1.w;
    }
    if (j < end) {
        int n = sorted_node[j];
        float4 v = reinterpret_cast<const float4*>(
                       node_feats + (size_t)n * HIDDEN)[sub];
        a0.x += v.x; a0.y += v.y; a0.z += v.z; a0.w += v.w;
    }

    float4 acc;
    acc.x = a0.x + a1.x;
    acc.y = a0.y + a1.y;
    acc.z = a0.z + a1.z;
    acc.w = a0.w + a1.w;

    // fold lanes 32-63 into 0-31
    acc.x += __shfl_down(acc.x, 32, 64);
    acc.y += __shfl_down(acc.y, 32, 64);
    acc.z += __shfl_down(acc.z, 32, 64);
    acc.w += __shfl_down(acc.w, 32, 64);

    if (half == 0) {
        float c = fmaxf((float)(end - start), 1.0f);
        float4 r;
        r.x = acc.x / c;
        r.y = acc.y / c;
        r.z = acc.z / c;
        r.w = acc.w / c;
        reinterpret_cast<float4*>(out + (size_t)wave * HIDDEN)[sub] = r;
    }
}

extern "C" void kernel_launch(void* const* d_in, const int* in_sizes, int n_in,
                              void* d_out, int out_size, void* d_ws, size_t ws_size,
                              hipStream_t stream) {
    const int* he_index = (const int*)d_in[1];
    const float* node_feats = (const float*)d_in[0];
    float* out = (float*)d_out;

    int E      = in_sizes[1] / 2;      // 600000
    int num_he = out_size / HIDDEN;    // 50000

    // Workspace layout (ints): counts[num_he] | offsets[num_he+1] |
    //   cursor[num_he] | block_sums[COOP_G] | sorted_node[E]
    int* counts      = (int*)d_ws;
    int* offsets     = counts + num_he;
    int* cursor      = offsets + (num_he + 1);
    int* block_sums  = cursor + num_he;
    int* sorted_node = block_sums + COOP_G;

    void* args[] = {(void*)&he_index, (void*)&counts,     (void*)&offsets,
                    (void*)&cursor,   (void*)&block_sums, (void*)&sorted_node,
                    (void*)&E,        (void*)&num_he};
    hipLaunchCooperativeKernel(reinterpret_cast<void*>(build_csr),
                               dim3(COOP_G), dim3(COOP_T), args, 0, stream);

    {
        const int threads = 256;                 // 4 waves/block, 1 wave/he
        const int blocks = (num_he + 3) / 4;
        aggregate_kernel<<<blocks, threads, 0, stream>>>(
            node_feats, offsets, sorted_node, out, num_he);
    }
}

// Round 7
// 159.479 us; speedup vs baseline: 4.1569x; 4.1569x over previous
//
#include <hip/hip_runtime.h>

#define HIDDEN 128
#define CAP    64   // padded bucket capacity; deg ~ Poisson(12), P(>64) ~ 1e-34
#define SCAN_B 256

// ===========================================================================
// PATH A: padded buckets (3 dispatches: memset, fill, aggregate)
// ===========================================================================
__global__ void fill_kernel(const int* __restrict__ he_index,  // [2, E] flat
                            int* __restrict__ counts,          // [num_he]
                            int* __restrict__ slots,           // [num_he*CAP]
                            int E) {
    int e = blockIdx.x * blockDim.x + threadIdx.x;
    if (e >= E) return;
    int node = he_index[e];
    int he   = he_index[E + e];
    int pos  = atomicAdd(&counts[he], 1);
    if (pos < CAP) slots[(size_t)he * CAP + pos] = node;
}

// One wave per hyperedge. Member indices read directly from the padded slot
// array: slots[wave*CAP + j] with j uniform per half-wave is a broadcast
// load (same pattern as the verified CSR aggregate; NO __shfl broadcast —
// ds_bpermute from exec-masked-off lanes is undefined and was the round-6
// corruption suspect). Half-wave split: lanes 0-31 even slots, 32-63 odd;
// each lane gathers float4 (16B) so 32 lanes cover one full 128-float row.
// 4-deep unroll -> 4 independent gathers in flight per lane.
__global__ __launch_bounds__(256) void aggregate_padded(
    const float* __restrict__ node_feats,
    const int* __restrict__ counts,
    const int* __restrict__ slots,
    float* __restrict__ out,
    int num_he) {
    int wave = (blockIdx.x * blockDim.x + threadIdx.x) >> 6;
    int lane = threadIdx.x & 63;
    if (wave >= num_he) return;

    int deg  = counts[wave];
    int degc = deg < CAP ? deg : CAP;

    int half = lane >> 5;
    int sub  = lane & 31;
    const int* myslots = slots + (size_t)wave * CAP;

    float4 a0 = make_float4(0.f, 0.f, 0.f, 0.f);
    float4 a1 = make_float4(0.f, 0.f, 0.f, 0.f);
    float4 a2 = make_float4(0.f, 0.f, 0.f, 0.f);
    float4 a3 = make_float4(0.f, 0.f, 0.f, 0.f);

    int j = half;
    // 4-deep: slots j, j+2, j+4, j+6 (this half's stride-2 sequence)
    for (; j + 6 < degc; j += 8) {
        int n0 = myslots[j];
        int n1 = myslots[j + 2];
        int n2 = myslots[j + 4];
        int n3 = myslots[j + 6];
        float4 v0 = reinterpret_cast<const float4*>(
                        node_feats + (size_t)n0 * HIDDEN)[sub];
        float4 v1 = reinterpret_cast<const float4*>(
                        node_feats + (size_t)n1 * HIDDEN)[sub];
        float4 v2 = reinterpret_cast<const float4*>(
                        node_feats + (size_t)n2 * HIDDEN)[sub];
        float4 v3 = reinterpret_cast<const float4*>(
                        node_feats + (size_t)n3 * HIDDEN)[sub];
        a0.x += v0.x; a0.y += v0.y; a0.z += v0.z; a0.w += v0.w;
        a1.x += v1.x; a1.y += v1.y; a1.z += v1.z; a1.w += v1.w;
        a2.x += v2.x; a2.y += v2.y; a2.z += v2.z; a2.w += v2.w;
        a3.x += v3.x; a3.y += v3.y; a3.z += v3.z; a3.w += v3.w;
    }
    // 2-deep remainder
    for (; j + 2 < degc; j += 4) {
        int n0 = myslots[j];
        int n1 = myslots[j + 2];
        float4 v0 = reinterpret_cast<const float4*>(
                        node_feats + (size_t)n0 * HIDDEN)[sub];
        float4 v1 = reinterpret_cast<const float4*>(
                        node_feats + (size_t)n1 * HIDDEN)[sub];
        a0.x += v0.x; a0.y += v0.y; a0.z += v0.z; a0.w += v0.w;
        a1.x += v1.x; a1.y += v1.y; a1.z += v1.z; a1.w += v1.w;
    }
    // tail
    if (j < degc) {
        int n = myslots[j];
        float4 v = reinterpret_cast<const float4*>(
                       node_feats + (size_t)n * HIDDEN)[sub];
        a0.x += v.x; a0.y += v.y; a0.z += v.z; a0.w += v.w;
    }

    float4 acc;
    acc.x = (a0.x + a1.x) + (a2.x + a3.x);
    acc.y = (a0.y + a1.y) + (a2.y + a3.y);
    acc.z = (a0.z + a1.z) + (a2.z + a3.z);
    acc.w = (a0.w + a1.w) + (a2.w + a3.w);

    // fold lanes 32-63 into 0-31 (all lanes active here; converged)
    acc.x += __shfl_down(acc.x, 32, 64);
    acc.y += __shfl_down(acc.y, 32, 64);
    acc.z += __shfl_down(acc.z, 32, 64);
    acc.w += __shfl_down(acc.w, 32, 64);

    if (half == 0) {
        float c = fmaxf((float)deg, 1.0f);
        float4 r;
        r.x = acc.x / c;
        r.y = acc.y / c;
        r.z = acc.z / c;
        r.w = acc.w / c;
        reinterpret_cast<float4*>(out + (size_t)wave * HIDDEN)[sub] = r;
    }
}

// ===========================================================================
// PATH B (fallback if ws too small): round-4 CSR chain, known-good
// ===========================================================================
__global__ void hist_kernel(const int* __restrict__ he_index,
                            int* __restrict__ counts, int E) {
    int e = blockIdx.x * blockDim.x + threadIdx.x;
    if (e >= E) return;
    atomicAdd(&counts[he_index[E + e]], 1);
}

__global__ void scan1_block_sums(const int* __restrict__ counts,
                                 int* __restrict__ block_sums, int num_he) {
    int i = blockIdx.x * SCAN_B + threadIdx.x;
    int v = (i < num_he) ? counts[i] : 0;
    __shared__ int lds[SCAN_B];
    lds[threadIdx.x] = v;
    __syncthreads();
    for (int off = SCAN_B / 2; off > 0; off >>= 1) {
        if (threadIdx.x < off) lds[threadIdx.x] += lds[threadIdx.x + off];
        __syncthreads();
    }
    if (threadIdx.x == 0) block_sums[blockIdx.x] = lds[0];
}

__global__ void scan2_block_offsets(int* __restrict__ block_sums,
                                    int* __restrict__ offsets,
                                    int nblocks, int num_he) {
    __shared__ int lds[SCAN_B];
    int t = threadIdx.x;
    int v = (t < nblocks) ? block_sums[t] : 0;
    lds[t] = v;
    __syncthreads();
    for (int off = 1; off < SCAN_B; off <<= 1) {
        int tv = (t >= off) ? lds[t - off] : 0;
        __syncthreads();
        lds[t] += tv;
        __syncthreads();
    }
    if (t < nblocks) block_sums[t] = lds[t] - v;
    if (t == nblocks - 1) offsets[num_he] = lds[t];
}

__global__ void scan3_write_offsets(const int* __restrict__ counts,
                                    const int* __restrict__ block_sums,
                                    int* __restrict__ offsets,
                                    int* __restrict__ cursor, int num_he) {
    int i = blockIdx.x * SCAN_B + threadIdx.x;
    int v = (i < num_he) ? counts[i] : 0;
    __shared__ int lds[SCAN_B];
    lds[threadIdx.x] = v;
    __syncthreads();
    for (int off = 1; off < SCAN_B; off <<= 1) {
        int tv = (threadIdx.x >= off) ? lds[threadIdx.x - off] : 0;
        __syncthreads();
        lds[threadIdx.x] += tv;
        __syncthreads();
    }
    if (i < num_he) {
        int ex = lds[threadIdx.x] - v + block_sums[blockIdx.x];
        offsets[i] = ex;
        cursor[i]  = ex;
    }
}

__global__ void place_kernel(const int* __restrict__ he_index,
                             int* __restrict__ cursor,
                             int* __restrict__ sorted_node, int E) {
    int e = blockIdx.x * blockDim.x + threadIdx.x;
    if (e >= E) return;
    int node = he_index[e];
    int he   = he_index[E + e];
    int pos  = atomicAdd(&cursor[he], 1);
    sorted_node[pos] = node;
}

__global__ __launch_bounds__(256) void aggregate_csr(
    const float* __restrict__ node_feats,
    const int* __restrict__ offsets,
    const int* __restrict__ sorted_node,
    float* __restrict__ out, int num_he) {
    int wave = (blockIdx.x * blockDim.x + threadIdx.x) >> 6;
    int lane = threadIdx.x & 63;
    if (wave >= num_he) return;

    int start = offsets[wave];
    int end   = offsets[wave + 1];
    int half  = lane >> 5;
    int sub   = lane & 31;

    float4 a0 = make_float4(0.f, 0.f, 0.f, 0.f);
    float4 a1 = make_float4(0.f, 0.f, 0.f, 0.f);

    int j = start + half;
    for (; j + 2 < end; j += 4) {
        int n0 = sorted_node[j];
        int n1 = sorted_node[j + 2];
        float4 v0 = reinterpret_cast<const float4*>(
                        node_feats + (size_t)n0 * HIDDEN)[sub];
        float4 v1 = reinterpret_cast<const float4*>(
                        node_feats + (size_t)n1 * HIDDEN)[sub];
        a0.x += v0.x; a0.y += v0.y; a0.z += v0.z; a0.w += v0.w;
        a1.x += v1.x; a1.y += v1.y; a1.z += v1.z; a1.w += v1.w;
    }
    if (j < end) {
        int n = sorted_node[j];
        float4 v = reinterpret_cast<const float4*>(
                       node_feats + (size_t)n * HIDDEN)[sub];
        a0.x += v.x; a0.y += v.y; a0.z += v.z; a0.w += v.w;
    }

    float4 acc;
    acc.x = a0.x + a1.x;
    acc.y = a0.y + a1.y;
    acc.z = a0.z + a1.z;
    acc.w = a0.w + a1.w;
    acc.x += __shfl_down(acc.x, 32, 64);
    acc.y += __shfl_down(acc.y, 32, 64);
    acc.z += __shfl_down(acc.z, 32, 64);
    acc.w += __shfl_down(acc.w, 32, 64);

    if (half == 0) {
        float c = fmaxf((float)(end - start), 1.0f);
        float4 r;
        r.x = acc.x / c;
        r.y = acc.y / c;
        r.z = acc.z / c;
        r.w = acc.w / c;
        reinterpret_cast<float4*>(out + (size_t)wave * HIDDEN)[sub] = r;
    }
}

extern "C" void kernel_launch(void* const* d_in, const int* in_sizes, int n_in,
                              void* d_out, int out_size, void* d_ws, size_t ws_size,
                              hipStream_t stream) {
    const float* node_feats = (const float*)d_in[0];
    const int* he_index     = (const int*)d_in[1];
    float* out              = (float*)d_out;

    const int E      = in_sizes[1] / 2;      // 600000
    const int num_he = out_size / HIDDEN;    // 50000

    const size_t needA =
        (size_t)num_he * sizeof(int) + (size_t)num_he * CAP * sizeof(int);

    if (ws_size >= needA) {
        // ---- PATH A: counts[num_he] | slots[num_he*CAP] ----
        int* counts = (int*)d_ws;
        int* slots  = counts + num_he;

        hipMemsetAsync(counts, 0, (size_t)num_he * sizeof(int), stream);

        {
            const int threads = 256;
            const int blocks = (E + threads - 1) / threads;
            fill_kernel<<<blocks, threads, 0, stream>>>(he_index, counts,
                                                        slots, E);
        }
        {
            const int threads = 256;  // 4 waves/block, 1 wave/he
            const int blocks = (num_he + 3) / 4;
            aggregate_padded<<<blocks, threads, 0, stream>>>(
                node_feats, counts, slots, out, num_he);
        }
    } else {
        // ---- PATH B: counts | offsets | cursor | block_sums | sorted ----
        int* counts      = (int*)d_ws;
        int* offsets     = counts + num_he;
        int* cursor      = offsets + (num_he + 1);
        int* block_sums  = cursor + num_he;
        int* sorted_node = block_sums + SCAN_B;
        const int nblocks_scan = (num_he + SCAN_B - 1) / SCAN_B;

        hipMemsetAsync(counts, 0, (size_t)num_he * sizeof(int), stream);

        {
            const int threads = 256;
            const int blocks = (E + threads - 1) / threads;
            hist_kernel<<<blocks, threads, 0, stream>>>(he_index, counts, E);
        }
        scan1_block_sums<<<nblocks_scan, SCAN_B, 0, stream>>>(
            counts, block_sums, num_he);
        scan2_block_offsets<<<1, SCAN_B, 0, stream>>>(block_sums, offsets,
                                                      nblocks_scan, num_he);
        scan3_write_offsets<<<nblocks_scan, SCAN_B, 0, stream>>>(
            counts, block_sums, offsets, cursor, num_he);
        {
            const int threads = 256;
            const int blocks = (E + threads - 1) / threads;
            place_kernel<<<blocks, threads, 0, stream>>>(he_index, cursor,
                                                         sorted_node, E);
        }
        {
            const int threads = 256;
            const int blocks = (num_he + 3) / 4;
            aggregate_csr<<<blocks, threads, 0, stream>>>(
                node_feats, offsets, sorted_node, out, num_he);
        }
    }
}

// Round 8
// 159.035 us; speedup vs baseline: 4.1685x; 1.0028x over previous
//
#include <hip/hip_runtime.h>

#define HIDDEN 128
#define CAP    64   // padded bucket capacity; deg ~ Poisson(12), P(>64) ~ 1e-34
#define UNR    12   // unrolled slots per half-wave: covers deg <= 24 (99.93%)
#define SCAN_B 256

// ===========================================================================
// PATH A: padded buckets (3 dispatches: memset, fill, aggregate)
// ===========================================================================
__global__ void fill_kernel(const int* __restrict__ he_index,  // [2, E] flat
                            int* __restrict__ counts,          // [num_he]
                            int* __restrict__ slots,           // [num_he*CAP]
                            int E) {
    int e = blockIdx.x * blockDim.x + threadIdx.x;
    if (e >= E) return;
    int node = he_index[e];
    int he   = he_index[E + e];
    int pos  = atomicAdd(&counts[he], 1);
    if (pos < CAP) slots[(size_t)he * CAP + pos] = node;
}

// One wave per hyperedge; half-wave split (lanes 0-31 even slots, 32-63 odd;
// 32 lanes x float4 = one full 128-float row per gather instruction).
// Latency fix: fully-unrolled 12-slot pipeline per half — branchless
// (clamped slot index + 0/1 mask), loads staged before accumulation so all
// 12 gathers are in flight per lane. Dup loads of slot 0 (masked) are L1
// hits. Dynamic tail loop covers the rare deg > 24. No divergence anywhere
// (deg==0 early-out is wave-uniform), so the shfl fold is safe.
__global__ __launch_bounds__(256) void aggregate_padded(
    const float* __restrict__ node_feats,
    const int* __restrict__ counts,
    const int* __restrict__ slots,
    float* __restrict__ out,
    int num_he) {
    int wave = (blockIdx.x * blockDim.x + threadIdx.x) >> 6;
    int lane = threadIdx.x & 63;
    if (wave >= num_he) return;

    int deg  = counts[wave];
    int degc = deg < CAP ? deg : CAP;

    int half = lane >> 5;
    int sub  = lane & 31;
    const int* myslots = slots + (size_t)wave * CAP;

    if (degc == 0) {   // wave-uniform; reference yields 0 / max(0,1) = 0
        if (half == 0) {
            reinterpret_cast<float4*>(out + (size_t)wave * HIDDEN)[sub] =
                make_float4(0.f, 0.f, 0.f, 0.f);
        }
        return;
    }

    // ---- stage 1: issue all 12 gathers (independent, batched) ----
    float4 v[UNR];
    float  m[UNR];
    #pragma unroll
    for (int i = 0; i < UNR; ++i) {
        int j  = half + 2 * i;
        int jj = (j < degc) ? j : 0;         // slot 0 valid since degc >= 1
        m[i]   = (j < degc) ? 1.0f : 0.0f;
        int n  = myslots[jj];
        v[i]   = reinterpret_cast<const float4*>(
                     node_feats + (size_t)n * HIDDEN)[sub];
    }

    // ---- stage 2: masked accumulation (2 chains to shorten deps) ----
    float4 a0 = make_float4(0.f, 0.f, 0.f, 0.f);
    float4 a1 = make_float4(0.f, 0.f, 0.f, 0.f);
    #pragma unroll
    for (int i = 0; i < UNR; i += 2) {
        a0.x += v[i].x * m[i];  a0.y += v[i].y * m[i];
        a0.z += v[i].z * m[i];  a0.w += v[i].w * m[i];
        a1.x += v[i+1].x * m[i+1];  a1.y += v[i+1].y * m[i+1];
        a1.z += v[i+1].z * m[i+1];  a1.w += v[i+1].w * m[i+1];
    }

    // ---- rare tail: deg > 2*UNR (P ~ 7e-4) ----
    for (int j = half + 2 * UNR; j < degc; j += 2) {
        int n = myslots[j];
        float4 t = reinterpret_cast<const float4*>(
                       node_feats + (size_t)n * HIDDEN)[sub];
        a0.x += t.x; a0.y += t.y; a0.z += t.z; a0.w += t.w;
    }

    float4 acc;
    acc.x = a0.x + a1.x;
    acc.y = a0.y + a1.y;
    acc.z = a0.z + a1.z;
    acc.w = a0.w + a1.w;

    // fold lanes 32-63 into 0-31 (wave fully converged here)
    acc.x += __shfl_down(acc.x, 32, 64);
    acc.y += __shfl_down(acc.y, 32, 64);
    acc.z += __shfl_down(acc.z, 32, 64);
    acc.w += __shfl_down(acc.w, 32, 64);

    if (half == 0) {
        float c = fmaxf((float)deg, 1.0f);
        float4 r;
        r.x = acc.x / c;
        r.y = acc.y / c;
        r.z = acc.z / c;
        r.w = acc.w / c;
        reinterpret_cast<float4*>(out + (size_t)wave * HIDDEN)[sub] = r;
    }
}

// ===========================================================================
// PATH B (fallback if ws too small): round-4 CSR chain, known-good
// ===========================================================================
__global__ void hist_kernel(const int* __restrict__ he_index,
                            int* __restrict__ counts, int E) {
    int e = blockIdx.x * blockDim.x + threadIdx.x;
    if (e >= E) return;
    atomicAdd(&counts[he_index[E + e]], 1);
}

__global__ void scan1_block_sums(const int* __restrict__ counts,
                                 int* __restrict__ block_sums, int num_he) {
    int i = blockIdx.x * SCAN_B + threadIdx.x;
    int v = (i < num_he) ? counts[i] : 0;
    __shared__ int lds[SCAN_B];
    lds[threadIdx.x] = v;
    __syncthreads();
    for (int off = SCAN_B / 2; off > 0; off >>= 1) {
        if (threadIdx.x < off) lds[threadIdx.x] += lds[threadIdx.x + off];
        __syncthreads();
    }
    if (threadIdx.x == 0) block_sums[blockIdx.x] = lds[0];
}

__global__ void scan2_block_offsets(int* __restrict__ block_sums,
                                    int* __restrict__ offsets,
                                    int nblocks, int num_he) {
    __shared__ int lds[SCAN_B];
    int t = threadIdx.x;
    int v = (t < nblocks) ? block_sums[t] : 0;
    lds[t] = v;
    __syncthreads();
    for (int off = 1; off < SCAN_B; off <<= 1) {
        int tv = (t >= off) ? lds[t - off] : 0;
        __syncthreads();
        lds[t] += tv;
        __syncthreads();
    }
    if (t < nblocks) block_sums[t] = lds[t] - v;
    if (t == nblocks - 1) offsets[num_he] = lds[t];
}

__global__ void scan3_write_offsets(const int* __restrict__ counts,
                                    const int* __restrict__ block_sums,
                                    int* __restrict__ offsets,
                                    int* __restrict__ cursor, int num_he) {
    int i = blockIdx.x * SCAN_B + threadIdx.x;
    int v = (i < num_he) ? counts[i] : 0;
    __shared__ int lds[SCAN_B];
    lds[threadIdx.x] = v;
    __syncthreads();
    for (int off = 1; off < SCAN_B; off <<= 1) {
        int tv = (threadIdx.x >= off) ? lds[threadIdx.x - off] : 0;
        __syncthreads();
        lds[threadIdx.x] += tv;
        __syncthreads();
    }
    if (i < num_he) {
        int ex = lds[threadIdx.x] - v + block_sums[blockIdx.x];
        offsets[i] = ex;
        cursor[i]  = ex;
    }
}

__global__ void place_kernel(const int* __restrict__ he_index,
                             int* __restrict__ cursor,
                             int* __restrict__ sorted_node, int E) {
    int e = blockIdx.x * blockDim.x + threadIdx.x;
    if (e >= E) return;
    int node = he_index[e];
    int he   = he_index[E + e];
    int pos  = atomicAdd(&cursor[he], 1);
    sorted_node[pos] = node;
}

__global__ __launch_bounds__(256) void aggregate_csr(
    const float* __restrict__ node_feats,
    const int* __restrict__ offsets,
    const int* __restrict__ sorted_node,
    float* __restrict__ out, int num_he) {
    int wave = (blockIdx.x * blockDim.x + threadIdx.x) >> 6;
    int lane = threadIdx.x & 63;
    if (wave >= num_he) return;

    int start = offsets[wave];
    int end   = offsets[wave + 1];
    int half  = lane >> 5;
    int sub   = lane & 31;

    float4 a0 = make_float4(0.f, 0.f, 0.f, 0.f);
    float4 a1 = make_float4(0.f, 0.f, 0.f, 0.f);

    int j = start + half;
    for (; j + 2 < end; j += 4) {
        int n0 = sorted_node[j];
        int n1 = sorted_node[j + 2];
        float4 v0 = reinterpret_cast<const float4*>(
                        node_feats + (size_t)n0 * HIDDEN)[sub];
        float4 v1 = reinterpret_cast<const float4*>(
                        node_feats + (size_t)n1 * HIDDEN)[sub];
        a0.x += v0.x; a0.y += v0.y; a0.z += v0.z; a0.w += v0.w;
        a1.x += v1.x; a1.y += v1.y; a1.z += v1.z; a1.w += v1.w;
    }
    if (j < end) {
        int n = sorted_node[j];
        float4 v = reinterpret_cast<const float4*>(
                       node_feats + (size_t)n * HIDDEN)[sub];
        a0.x += v.x; a0.y += v.y; a0.z += v.z; a0.w += v.w;
    }

    float4 acc;
    acc.x = a0.x + a1.x;
    acc.y = a0.y + a1.y;
    acc.z = a0.z + a1.z;
    acc.w = a0.w + a1.w;
    acc.x += __shfl_down(acc.x, 32, 64);
    acc.y += __shfl_down(acc.y, 32, 64);
    acc.z += __shfl_down(acc.z, 32, 64);
    acc.w += __shfl_down(acc.w, 32, 64);

    if (half == 0) {
        float c = fmaxf((float)(end - start), 1.0f);
        float4 r;
        r.x = acc.x / c;
        r.y = acc.y / c;
        r.z = acc.z / c;
        r.w = acc.w / c;
        reinterpret_cast<float4*>(out + (size_t)wave * HIDDEN)[sub] = r;
    }
}

extern "C" void kernel_launch(void* const* d_in, const int* in_sizes, int n_in,
                              void* d_out, int out_size, void* d_ws, size_t ws_size,
                              hipStream_t stream) {
    const float* node_feats = (const float*)d_in[0];
    const int* he_index     = (const int*)d_in[1];
    float* out              = (float*)d_out;

    const int E      = in_sizes[1] / 2;      // 600000
    const int num_he = out_size / HIDDEN;    // 50000

    const size_t needA =
        (size_t)num_he * sizeof(int) + (size_t)num_he * CAP * sizeof(int);

    if (ws_size >= needA) {
        // ---- PATH A: counts[num_he] | slots[num_he*CAP] ----
        int* counts = (int*)d_ws;
        int* slots  = counts + num_he;

        hipMemsetAsync(counts, 0, (size_t)num_he * sizeof(int), stream);

        {
            const int threads = 256;
            const int blocks = (E + threads - 1) / threads;
            fill_kernel<<<blocks, threads, 0, stream>>>(he_index, counts,
                                                        slots, E);
        }
        {
            const int threads = 256;  // 4 waves/block, 1 wave/he
            const int blocks = (num_he + 3) / 4;
            aggregate_padded<<<blocks, threads, 0, stream>>>(
                node_feats, counts, slots, out, num_he);
        }
    } else {
        // ---- PATH B: counts | offsets | cursor | block_sums | sorted ----
        int* counts      = (int*)d_ws;
        int* offsets     = counts + num_he;
        int* cursor      = offsets + (num_he + 1);
        int* block_sums  = cursor + num_he;
        int* sorted_node = block_sums + SCAN_B;
        const int nblocks_scan = (num_he + SCAN_B - 1) / SCAN_B;

        hipMemsetAsync(counts, 0, (size_t)num_he * sizeof(int), stream);

        {
            const int threads = 256;
            const int blocks = (E + threads - 1) / threads;
            hist_kernel<<<blocks, threads, 0, stream>>>(he_index, counts, E);
        }
        scan1_block_sums<<<nblocks_scan, SCAN_B, 0, stream>>>(
            counts, block_sums, num_he);
        scan2_block_offsets<<<1, SCAN_B, 0, stream>>>(block_sums, offsets,
                                                      nblocks_scan, num_he);
        scan3_write_offsets<<<nblocks_scan, SCAN_B, 0, stream>>>(
            counts, block_sums, offsets, cursor, num_he);
        {
            const int threads = 256;
            const int blocks = (E + threads - 1) / threads;
            place_kernel<<<blocks, threads, 0, stream>>>(he_index, cursor,
                                                         sorted_node, E);
        }
        {
            const int threads = 256;
            const int blocks = (num_he + 3) / 4;
            aggregate_csr<<<blocks, threads, 0, stream>>>(
                node_feats, offsets, sorted_node, out, num_he);
        }
    }
}

// Round 9
// 157.212 us; speedup vs baseline: 4.2169x; 1.0116x over previous
//
#include <hip/hip_runtime.h>

#define HIDDEN 128
#define CAP    64   // padded bucket capacity; deg ~ Poisson(12), P(>64) ~ 1e-34
#define SCAN_B 256

// ===========================================================================
// PATH A: padded buckets (3 dispatches: memset, fill, aggregate)
// ===========================================================================
__global__ void fill_kernel(const int* __restrict__ he_index,  // [2, E] flat
                            int* __restrict__ counts,          // [num_he]
                            int* __restrict__ slots,           // [num_he*CAP]
                            int E) {
    int e = blockIdx.x * blockDim.x + threadIdx.x;
    if (e >= E) return;
    int node = he_index[e];
    int he   = he_index[E + e];
    int pos  = atomicAdd(&counts[he], 1);
    if (pos < CAP) slots[(size_t)he * CAP + pos] = node;
}

// Gather U rows for this half-wave (slots half, half+2, ..., half+2(U-1)),
// staged: indices first, then all U row-loads issued back-to-back, then
// masked accumulation. U covers degc <= 2*U.
template <int U>
__device__ __forceinline__ void gather_rows(
    const float* __restrict__ node_feats,
    const int* __restrict__ myslots,
    int degc, int half, int sub,
    float4& a0, float4& a1) {
    int   idx[U];
    float m[U];
#pragma unroll
    for (int i = 0; i < U; ++i) {
        int j  = half + 2 * i;
        m[i]   = (j < degc) ? 1.0f : 0.0f;
        idx[i] = myslots[(j < degc) ? j : 0];  // slot 0 valid (degc >= 1)
    }
    float4 v[U];
#pragma unroll
    for (int i = 0; i < U; ++i) {
        v[i] = reinterpret_cast<const float4*>(
                   node_feats + (size_t)idx[i] * HIDDEN)[sub];
    }
#pragma unroll
    for (int i = 0; i < U; i += 2) {
        a0.x += v[i].x * m[i];  a0.y += v[i].y * m[i];
        a0.z += v[i].z * m[i];  a0.w += v[i].w * m[i];
        a1.x += v[i + 1].x * m[i + 1];  a1.y += v[i + 1].y * m[i + 1];
        a1.z += v[i + 1].z * m[i + 1];  a1.w += v[i + 1].w * m[i + 1];
    }
}

// One wave per hyperedge; half-wave split (lanes 0-31 even slots, 32-63 odd;
// 32 lanes x float4 = one full 128-float row per gather instruction).
// degc is wave-uniform -> branch (no divergence) to the smallest unroll
// covering it: U in {4,8,12,16} for deg <= {8,16,24,32}; dynamic tail for
// the vanishing deg > 32. __launch_bounds__(256,4) allows 128 VGPR so the
// staged loads genuinely stay in flight.
__global__ __launch_bounds__(256, 4) void aggregate_padded(
    const float* __restrict__ node_feats,
    const int* __restrict__ counts,
    const int* __restrict__ slots,
    float* __restrict__ out,
    int num_he) {
    int wave = (blockIdx.x * blockDim.x + threadIdx.x) >> 6;
    int lane = threadIdx.x & 63;
    if (wave >= num_he) return;

    int deg  = counts[wave];
    int degc = deg < CAP ? deg : CAP;

    int half = lane >> 5;
    int sub  = lane & 31;
    const int* myslots = slots + (size_t)wave * CAP;

    if (degc == 0) {   // wave-uniform; reference yields 0 / max(0,1) = 0
        if (half == 0) {
            reinterpret_cast<float4*>(out + (size_t)wave * HIDDEN)[sub] =
                make_float4(0.f, 0.f, 0.f, 0.f);
        }
        return;
    }

    float4 a0 = make_float4(0.f, 0.f, 0.f, 0.f);
    float4 a1 = make_float4(0.f, 0.f, 0.f, 0.f);

    if (degc <= 8) {
        gather_rows<4>(node_feats, myslots, degc, half, sub, a0, a1);
    } else if (degc <= 16) {
        gather_rows<8>(node_feats, myslots, degc, half, sub, a0, a1);
    } else if (degc <= 24) {
        gather_rows<12>(node_feats, myslots, degc, half, sub, a0, a1);
    } else {
        gather_rows<16>(node_feats, myslots, degc, half, sub, a0, a1);
        // dynamic tail: deg > 32 (P ~ 2e-5); no cross-lane ops inside
        for (int j = half + 32; j < degc; j += 2) {
            int n = myslots[j];
            float4 t = reinterpret_cast<const float4*>(
                           node_feats + (size_t)n * HIDDEN)[sub];
            a0.x += t.x; a0.y += t.y; a0.z += t.z; a0.w += t.w;
        }
    }

    float4 acc;
    acc.x = a0.x + a1.x;
    acc.y = a0.y + a1.y;
    acc.z = a0.z + a1.z;
    acc.w = a0.w + a1.w;

    // fold lanes 32-63 into 0-31 (wave fully converged here)
    acc.x += __shfl_down(acc.x, 32, 64);
    acc.y += __shfl_down(acc.y, 32, 64);
    acc.z += __shfl_down(acc.z, 32, 64);
    acc.w += __shfl_down(acc.w, 32, 64);

    if (half == 0) {
        float c = fmaxf((float)deg, 1.0f);
        float4 r;
        r.x = acc.x / c;
        r.y = acc.y / c;
        r.z = acc.z / c;
        r.w = acc.w / c;
        reinterpret_cast<float4*>(out + (size_t)wave * HIDDEN)[sub] = r;
    }
}

// ===========================================================================
// PATH B (fallback if ws too small): round-4 CSR chain, known-good
// ===========================================================================
__global__ void hist_kernel(const int* __restrict__ he_index,
                            int* __restrict__ counts, int E) {
    int e = blockIdx.x * blockDim.x + threadIdx.x;
    if (e >= E) return;
    atomicAdd(&counts[he_index[E + e]], 1);
}

__global__ void scan1_block_sums(const int* __restrict__ counts,
                                 int* __restrict__ block_sums, int num_he) {
    int i = blockIdx.x * SCAN_B + threadIdx.x;
    int v = (i < num_he) ? counts[i] : 0;
    __shared__ int lds[SCAN_B];
    lds[threadIdx.x] = v;
    __syncthreads();
    for (int off = SCAN_B / 2; off > 0; off >>= 1) {
        if (threadIdx.x < off) lds[threadIdx.x] += lds[threadIdx.x + off];
        __syncthreads();
    }
    if (threadIdx.x == 0) block_sums[blockIdx.x] = lds[0];
}

__global__ void scan2_block_offsets(int* __restrict__ block_sums,
                                    int* __restrict__ offsets,
                                    int nblocks, int num_he) {
    __shared__ int lds[SCAN_B];
    int t = threadIdx.x;
    int v = (t < nblocks) ? block_sums[t] : 0;
    lds[t] = v;
    __syncthreads();
    for (int off = 1; off < SCAN_B; off <<= 1) {
        int tv = (t >= off) ? lds[t - off] : 0;
        __syncthreads();
        lds[t] += tv;
        __syncthreads();
    }
    if (t < nblocks) block_sums[t] = lds[t] - v;
    if (t == nblocks - 1) offsets[num_he] = lds[t];
}

__global__ void scan3_write_offsets(const int* __restrict__ counts,
                                    const int* __restrict__ block_sums,
                                    int* __restrict__ offsets,
                                    int* __restrict__ cursor, int num_he) {
    int i = blockIdx.x * SCAN_B + threadIdx.x;
    int v = (i < num_he) ? counts[i] : 0;
    __shared__ int lds[SCAN_B];
    lds[threadIdx.x] = v;
    __syncthreads();
    for (int off = 1; off < SCAN_B; off <<= 1) {
        int tv = (threadIdx.x >= off) ? lds[threadIdx.x - off] : 0;
        __syncthreads();
        lds[threadIdx.x] += tv;
        __syncthreads();
    }
    if (i < num_he) {
        int ex = lds[threadIdx.x] - v + block_sums[blockIdx.x];
        offsets[i] = ex;
        cursor[i]  = ex;
    }
}

__global__ void place_kernel(const int* __restrict__ he_index,
                             int* __restrict__ cursor,
                             int* __restrict__ sorted_node, int E) {
    int e = blockIdx.x * blockDim.x + threadIdx.x;
    if (e >= E) return;
    int node = he_index[e];
    int he   = he_index[E + e];
    int pos  = atomicAdd(&cursor[he], 1);
    sorted_node[pos] = node;
}

__global__ __launch_bounds__(256) void aggregate_csr(
    const float* __restrict__ node_feats,
    const int* __restrict__ offsets,
    const int* __restrict__ sorted_node,
    float* __restrict__ out, int num_he) {
    int wave = (blockIdx.x * blockDim.x + threadIdx.x) >> 6;
    int lane = threadIdx.x & 63;
    if (wave >= num_he) return;

    int start = offsets[wave];
    int end   = offsets[wave + 1];
    int half  = lane >> 5;
    int sub   = lane & 31;

    float4 a0 = make_float4(0.f, 0.f, 0.f, 0.f);
    float4 a1 = make_float4(0.f, 0.f, 0.f, 0.f);

    int j = start + half;
    for (; j + 2 < end; j += 4) {
        int n0 = sorted_node[j];
        int n1 = sorted_node[j + 2];
        float4 v0 = reinterpret_cast<const float4*>(
                        node_feats + (size_t)n0 * HIDDEN)[sub];
        float4 v1 = reinterpret_cast<const float4*>(
                        node_feats + (size_t)n1 * HIDDEN)[sub];
        a0.x += v0.x; a0.y += v0.y; a0.z += v0.z; a0.w += v0.w;
        a1.x += v1.x; a1.y += v1.y; a1.z += v1.z; a1.w += v1.w;
    }
    if (j < end) {
        int n = sorted_node[j];
        float4 v = reinterpret_cast<const float4*>(
                       node_feats + (size_t)n * HIDDEN)[sub];
        a0.x += v.x; a0.y += v.y; a0.z += v.z; a0.w += v.w;
    }

    float4 acc;
    acc.x = a0.x + a1.x;
    acc.y = a0.y + a1.y;
    acc.z = a0.z + a1.z;
    acc.w = a0.w + a1.w;
    acc.x += __shfl_down(acc.x, 32, 64);
    acc.y += __shfl_down(acc.y, 32, 64);
    acc.z += __shfl_down(acc.z, 32, 64);
    acc.w += __shfl_down(acc.w, 32, 64);

    if (half == 0) {
        float c = fmaxf((float)(end - start), 1.0f);
        float4 r;
        r.x = acc.x / c;
        r.y = acc.y / c;
        r.z = acc.z / c;
        r.w = acc.w / c;
        reinterpret_cast<float4*>(out + (size_t)wave * HIDDEN)[sub] = r;
    }
}

extern "C" void kernel_launch(void* const* d_in, const int* in_sizes, int n_in,
                              void* d_out, int out_size, void* d_ws, size_t ws_size,
                              hipStream_t stream) {
    const float* node_feats = (const float*)d_in[0];
    const int* he_index     = (const int*)d_in[1];
    float* out              = (float*)d_out;

    const int E      = in_sizes[1] / 2;      // 600000
    const int num_he = out_size / HIDDEN;    // 50000

    const size_t needA =
        (size_t)num_he * sizeof(int) + (size_t)num_he * CAP * sizeof(int);

    if (ws_size >= needA) {
        // ---- PATH A: counts[num_he] | slots[num_he*CAP] ----
        int* counts = (int*)d_ws;
        int* slots  = counts + num_he;

        hipMemsetAsync(counts, 0, (size_t)num_he * sizeof(int), stream);

        {
            const int threads = 256;
            const int blocks = (E + threads - 1) / threads;
            fill_kernel<<<blocks, threads, 0, stream>>>(he_index, counts,
                                                        slots, E);
        }
        {
            const int threads = 256;  // 4 waves/block, 1 wave/he
            const int blocks = (num_he + 3) / 4;
            aggregate_padded<<<blocks, threads, 0, stream>>>(
                node_feats, counts, slots, out, num_he);
        }
    } else {
        // ---- PATH B: counts | offsets | cursor | block_sums | sorted ----
        int* counts      = (int*)d_ws;
        int* offsets     = counts + num_he;
        int* cursor      = offsets + (num_he + 1);
        int* block_sums  = cursor + num_he;
        int* sorted_node = block_sums + SCAN_B;
        const int nblocks_scan = (num_he + SCAN_B - 1) / SCAN_B;

        hipMemsetAsync(counts, 0, (size_t)num_he * sizeof(int), stream);

        {
            const int threads = 256;
            const int blocks = (E + threads - 1) / threads;
            hist_kernel<<<blocks, threads, 0, stream>>>(he_index, counts, E);
        }
        scan1_block_sums<<<nblocks_scan, SCAN_B, 0, stream>>>(
            counts, block_sums, num_he);
        scan2_block_offsets<<<1, SCAN_B, 0, stream>>>(block_sums, offsets,
                                                      nblocks_scan, num_he);
        scan3_write_offsets<<<nblocks_scan, SCAN_B, 0, stream>>>(
            counts, block_sums, offsets, cursor, num_he);
        {
            const int threads = 256;
            const int blocks = (E + threads - 1) / threads;
            place_kernel<<<blocks, threads, 0, stream>>>(he_index, cursor,
                                                         sorted_node, E);
        }
        {
            const int threads = 256;
            const int blocks = (num_he + 3) / 4;
            aggregate_csr<<<blocks, threads, 0, stream>>>(
                node_feats, offsets, sorted_node, out, num_he);
        }
    }
}